// Round 5
// baseline (248.384 us; speedup 1.0000x reference)
//
#include <hip/hip_runtime.h>
#include <math.h>

#define Bv 4
#define Nv 256
#define Cv 32
#define Mv 4
#define OUTv 64
#define MCv (Mv*Cv)      // 128

typedef _Float16 h8 __attribute__((ext_vector_type(8)));
typedef _Float16 h4 __attribute__((ext_vector_type(4)));
typedef float f4 __attribute__((ext_vector_type(4)));

// ---- static device scratch ----
__device__ __align__(16) float g_rs  [Bv * Nv * Cv];
__device__ __align__(16) float g_cs  [Bv * Nv * Cv];
__device__ __align__(16) float g_dgx [Bv * Nv * Cv];
__device__ __align__(16) float g_nb  [Bv * Nv * Mv];
__device__ __align__(16) float g_S1  [Bv * Nv * MCv];
__device__ __align__(16) float g_S2  [Bv * Nv * MCv];
__device__ __align__(16) float g_rcs2[Bv * MCv];        // atomic accum
__device__ __align__(16) float g_ds2 [Bv * MCv];        // atomic accum
__device__ __align__(16) float g_t0g [Bv * OUTv];
__device__ __align__(16) float g_addv[Bv * Nv * OUTv];
__device__ __align__(16) _Float16 g_wfrag[8 * 4 * 64 * 8];   // 32 KB

// ---------------- K0: pack w2d -> f16 fragment order + zero accumulators ------
__global__ void k_wpackz(const float* __restrict__ w2d) {
    int t = threadIdx.x;
    int r = blockIdx.x;
    if (r == 8) {   // zero rcs2/ds2 (atomic accumulators)
        if (t < 128) ((float4*)g_rcs2)[t] = {0.f,0.f,0.f,0.f};
        else         ((float4*)g_ds2)[t - 128] = {0.f,0.f,0.f,0.f};
        return;
    }
    int fi = r * 256 + t;
    int s = fi >> 8, q = (fi >> 6) & 3, lane = fi & 63;
    int k0 = s * 32 + ((lane >> 4) << 3);
    int o = q * 16 + (lane & 15);
    #pragma unroll
    for (int jj = 0; jj < 8; jj++)
        g_wfrag[fi * 8 + jj] = (_Float16)w2d[(size_t)(k0 + jj) * OUTv + o];
}

// ---------------- PassA: rs (col-band) + dgx, cs (row-band) -------------------
// col-band block (bx<32): j0=bx*8; rs[j,c] = (1/N) sum_i x[i,j,c]; dgx diag
// row-band block (bx>=32): i0=(bx-32)*8; cs[i,c] = (1/N) sum_j x[i,j,c]
__global__ __launch_bounds__(256) void k_passA(const float* __restrict__ x) {
    int b = blockIdx.y;
    const float4* x4 = (const float4*)(x + (size_t)b * Nv * Nv * Cv);
    int t = threadIdx.x;
    __shared__ __align__(16) float4 red[256];
    if (blockIdx.x < 32) {
        int j0 = blockIdx.x * 8;
        int isub = t >> 6, jc = (t >> 3) & 7, c4 = t & 7;
        int jrow = j0 + jc;
        float4 acc = {0.f,0.f,0.f,0.f};
        for (int i = isub; i < Nv; i += 4) {
            float4 v = x4[((size_t)i * Nv + jrow) * 8 + c4];
            acc.x += v.x; acc.y += v.y; acc.z += v.z; acc.w += v.w;
            if (i == jrow) ((float4*)g_dgx)[(b * Nv + i) * 8 + c4] = v;
        }
        red[t] = acc;           // [isub][jc][c4]
        __syncthreads();
        if (t < 64) {
            float4 s = red[t];
            #pragma unroll
            for (int k = 1; k < 4; k++) {
                float4 v = red[k * 64 + t];
                s.x += v.x; s.y += v.y; s.z += v.z; s.w += v.w;
            }
            const float sc = 1.0f / Nv;
            s.x *= sc; s.y *= sc; s.z *= sc; s.w *= sc;
            int jc2 = t >> 3, c42 = t & 7;
            ((float4*)g_rs)[(b * Nv + j0 + jc2) * 8 + c42] = s;
        }
    } else {
        int i0 = (blockIdx.x - 32) * 8;
        int ic = t >> 5, jsub = (t >> 3) & 3, c4 = t & 7;
        int irow = i0 + ic;
        float4 acc = {0.f,0.f,0.f,0.f};
        for (int jj = 0; jj < 64; jj++) {
            int j = jsub + jj * 4;
            float4 v = x4[((size_t)irow * Nv + j) * 8 + c4];
            acc.x += v.x; acc.y += v.y; acc.z += v.z; acc.w += v.w;
        }
        red[t] = acc;           // [ic][jsub][c4]
        __syncthreads();
        if (t < 64) {
            int ic2 = t >> 3, c42 = t & 7;
            float4 s = {0.f,0.f,0.f,0.f};
            #pragma unroll
            for (int k = 0; k < 4; k++) {
                float4 v = red[ic2 * 32 + k * 8 + c42];
                s.x += v.x; s.y += v.y; s.z += v.z; s.w += v.w;
            }
            const float sc = 1.0f / Nv;
            s.x *= sc; s.y *= sc; s.z *= sc; s.w *= sc;
            ((float4*)g_cs)[(b * Nv + i0 + ic2) * 8 + c42] = s;
        }
    }
}

// ---------------- K2: neighborhood linear + sigmoid ----------------
__global__ void k_neighb(const float* __restrict__ w1, const float* __restrict__ b1,
                         const float* __restrict__ w0, const float* __restrict__ b0) {
    int b = blockIdx.x, t = threadIdx.x;
    int c = t & 31, sub = t >> 5;
    float ar = 0.f, ad = 0.f;
    for (int n = sub; n < Nv; n += 8) {
        ar += g_rs[(b * Nv + n) * Cv + c];
        ad += g_dgx[(b * Nv + n) * Cv + c];
    }
    __shared__ float red[8][64];
    __shared__ float obj0[64];
    __shared__ float t0nb[4];
    red[sub][c] = ar;
    red[sub][32 + c] = ad;
    __syncthreads();
    if (t < 64) {
        float s = 0.f;
        #pragma unroll
        for (int k = 0; k < 8; k++) s += red[k][t];
        obj0[t] = s * (1.0f / Nv);
    }
    __syncthreads();
    if (t < 4) {
        float v = b0[t];
        for (int k = 0; k < 2 * Cv; k++) v += obj0[k] * w0[k * Mv + t];
        t0nb[t] = v;
    }
    __syncthreads();
    int n = t;
    float node[4];
    #pragma unroll
    for (int m = 0; m < 4; m++) node[m] = t0nb[m] + b1[m];
    for (int cc = 0; cc < Cv; cc++) {
        float r = g_rs[(b * Nv + n) * Cv + cc];
        float s = g_cs[(b * Nv + n) * Cv + cc];
        float d = g_dgx[(b * Nv + n) * Cv + cc];
        #pragma unroll
        for (int m = 0; m < 4; m++)
            node[m] += r * w1[cc * Mv + m] + s * w1[(Cv + cc) * Mv + m] + d * w1[(2 * Cv + cc) * Mv + m];
    }
    #pragma unroll
    for (int m = 0; m < 4; m++)
        g_nb[(b * Nv + n) * Mv + m] = 1.0f / (1.0f + expf(-node[m]));
}

// ---------------- PassB: S1 (col-band, + rcs2/ds2), S2 (row-band) -------------
// S1[j,m,c] = sum_i nb[i,m] x[i,j,c];  S2[i,m,c] = sum_j nb[j,m] x[i,j,c]
__global__ __launch_bounds__(256) void k_passB(const float* __restrict__ x) {
    int b = blockIdx.y;
    int t = threadIdx.x;
    __shared__ __align__(16) float nbs[Nv * Mv];      // 4 KB
    __shared__ __align__(16) float4 red[4 * 256];     // 16 KB: [m][thread]
    ((float4*)nbs)[t] = ((const float4*)(g_nb + (size_t)b * Nv * Mv))[t];
    __syncthreads();
    const float4* x4 = (const float4*)(x + (size_t)b * Nv * Nv * Cv);
    if (blockIdx.x < 32) {
        int j0 = blockIdx.x * 8;
        int isub = t >> 6, jc = (t >> 3) & 7, c4 = t & 7;
        int jrow = j0 + jc;
        float4 acc[4];
        #pragma unroll
        for (int m = 0; m < 4; m++) acc[m] = {0.f,0.f,0.f,0.f};
        float4 diagv = {0.f,0.f,0.f,0.f};
        for (int i = isub; i < Nv; i += 4) {
            float4 v = x4[((size_t)i * Nv + jrow) * 8 + c4];
            float4 w = *(const float4*)&nbs[i * 4];
            acc[0].x += w.x*v.x; acc[0].y += w.x*v.y; acc[0].z += w.x*v.z; acc[0].w += w.x*v.w;
            acc[1].x += w.y*v.x; acc[1].y += w.y*v.y; acc[1].z += w.y*v.z; acc[1].w += w.y*v.w;
            acc[2].x += w.z*v.x; acc[2].y += w.z*v.y; acc[2].z += w.z*v.z; acc[2].w += w.z*v.w;
            acc[3].x += w.w*v.x; acc[3].y += w.w*v.y; acc[3].z += w.w*v.z; acc[3].w += w.w*v.w;
            if (i == jrow) diagv = v;
        }
        #pragma unroll
        for (int m = 0; m < 4; m++) red[m * 256 + t] = acc[m];
        __syncthreads();
        if (t < 64) {
            int jc2 = t >> 3, c42 = t & 7;
            int n = j0 + jc2;
            #pragma unroll
            for (int m = 0; m < 4; m++) {
                float4 s = red[m * 256 + t];
                #pragma unroll
                for (int k = 1; k < 4; k++) {
                    float4 v = red[m * 256 + k * 64 + t];
                    s.x += v.x; s.y += v.y; s.z += v.z; s.w += v.w;
                }
                ((float4*)g_S1)[((size_t)(b * Nv + n)) * 32 + m * 8 + c42] = s;
                // rcs2 partial: sum_j nb[j,m]*S1[j,mc]
                float nv = nbs[n * 4 + m];
                atomicAdd(&g_rcs2[b * MCv + m * 32 + c42 * 4 + 0], nv * s.x);
                atomicAdd(&g_rcs2[b * MCv + m * 32 + c42 * 4 + 1], nv * s.y);
                atomicAdd(&g_rcs2[b * MCv + m * 32 + c42 * 4 + 2], nv * s.z);
                atomicAdd(&g_rcs2[b * MCv + m * 32 + c42 * 4 + 3], nv * s.w);
            }
        }
        // ds2 partial: sum_n nb[n,m]^2 * dgx[n,c] (diag holder threads only)
        if ((jrow & 3) == isub) {
            #pragma unroll
            for (int m = 0; m < 4; m++) {
                float nv = nbs[jrow * 4 + m];
                float w2 = nv * nv;
                atomicAdd(&g_ds2[b * MCv + m * 32 + c4 * 4 + 0], w2 * diagv.x);
                atomicAdd(&g_ds2[b * MCv + m * 32 + c4 * 4 + 1], w2 * diagv.y);
                atomicAdd(&g_ds2[b * MCv + m * 32 + c4 * 4 + 2], w2 * diagv.z);
                atomicAdd(&g_ds2[b * MCv + m * 32 + c4 * 4 + 3], w2 * diagv.w);
            }
        }
    } else {
        int i0 = (blockIdx.x - 32) * 8;
        int ic = t >> 5, jsub = (t >> 3) & 3, c4 = t & 7;
        int irow = i0 + ic;
        float4 acc[4];
        #pragma unroll
        for (int m = 0; m < 4; m++) acc[m] = {0.f,0.f,0.f,0.f};
        for (int jj = 0; jj < 64; jj++) {
            int j = jsub + jj * 4;
            float4 v = x4[((size_t)irow * Nv + j) * 8 + c4];
            float4 w = *(const float4*)&nbs[j * 4];
            acc[0].x += w.x*v.x; acc[0].y += w.x*v.y; acc[0].z += w.x*v.z; acc[0].w += w.x*v.w;
            acc[1].x += w.y*v.x; acc[1].y += w.y*v.y; acc[1].z += w.y*v.z; acc[1].w += w.y*v.w;
            acc[2].x += w.z*v.x; acc[2].y += w.z*v.y; acc[2].z += w.z*v.z; acc[2].w += w.z*v.w;
            acc[3].x += w.w*v.x; acc[3].y += w.w*v.y; acc[3].z += w.w*v.z; acc[3].w += w.w*v.w;
        }
        #pragma unroll
        for (int m = 0; m < 4; m++) red[m * 256 + t] = acc[m];
        __syncthreads();
        if (t < 64) {
            int ic2 = t >> 3, c42 = t & 7;
            #pragma unroll
            for (int m = 0; m < 4; m++) {
                float4 s = {0.f,0.f,0.f,0.f};
                #pragma unroll
                for (int k = 0; k < 4; k++) {
                    float4 v = red[m * 256 + ic2 * 32 + k * 8 + c42];
                    s.x += v.x; s.y += v.y; s.z += v.z; s.w += v.w;
                }
                ((float4*)g_S2)[((size_t)(b * Nv + i0 + ic2)) * 32 + m * 8 + c42] = s;
            }
        }
    }
}

// ---------------- K4a: global term t0[b,o] (tiny matvec) ----------------
__global__ void k_t0(const float* __restrict__ w0d, const float* __restrict__ b0d) {
    int b = blockIdx.x, t = threadIdx.x;   // 128 threads
    __shared__ float rc[MCv], ds[MCv];
    rc[t] = g_rcs2[b * MCv + t] * (1.0f / ((float)Nv * Nv));
    ds[t] = g_ds2 [b * MCv + t] * (1.0f / Nv);
    __syncthreads();
    if (t < OUTv) {
        float v = b0d[t];
        for (int k = 0; k < MCv; k++)
            v += rc[k] * w0d[k * OUTv + t] + ds[k] * w0d[(MCv + k) * OUTv + t];
        g_t0g[b * OUTv + t] = v;
    }
}

// ---------------- K4b: per-column additive term add[b,j,o] ----------------
__global__ void k_add(const float* __restrict__ w1d, const float* __restrict__ b1d,
                      const float* __restrict__ b2d) {
    int b = blockIdx.y;
    int n = blockIdx.x * 4 + (threadIdx.x >> 6);
    int o = threadIdx.x & 63;
    float acc = b1d[o] + b2d[o] + g_t0g[b * OUTv + o];
    const float invN = 1.0f / Nv;
    #pragma unroll
    for (int m = 0; m < 4; m++) {
        float nv = g_nb[(b * Nv + n) * Mv + m];
        float f = nv * invN, d2 = nv * nv;
        for (int c = 0; c < Cv; c++) {
            int mc = m * Cv + c;
            acc += f * g_S1[(size_t)(b * Nv + n) * MCv + mc] * w1d[mc * OUTv + o]
                 + f * g_S2[(size_t)(b * Nv + n) * MCv + mc] * w1d[(MCv + mc) * OUTv + o]
                 + d2 * g_dgx[(b * Nv + n) * Cv + c] * w1d[(2 * MCv + mc) * OUTv + o];
        }
    }
    g_addv[(size_t)(b * Nv + n) * OUTv + o] = acc;
}

// ---------------- K5: main term via MFMA f16 ----------------
#define XPAD 40
__global__ __launch_bounds__(256) void k_main(const float* __restrict__ x,
                                              float* __restrict__ out) {
    int jt = blockIdx.x, i = blockIdx.y, b = blockIdx.z;
    int j0 = jt * 128;
    int t = threadIdx.x;
    int lane = t & 63, w = t >> 6;
    int rowA = lane & 15, quad = lane >> 4;

    __shared__ __align__(16) _Float16 Wl[8 * 4 * 64 * 8];   // 32 KB
    __shared__ __align__(16) _Float16 Xt[128 * XPAD];
    __shared__ __align__(16) _Float16 Xb[128 * XPAD];

    {
        const float4* src = (const float4*)g_wfrag;
        float4* dst = (float4*)Wl;
        #pragma unroll
        for (int r = 0; r < 8; r++) dst[r * 256 + t] = src[r * 256 + t];
    }
    {
        const float4* x4 = (const float4*)x;
        #pragma unroll
        for (int r = 0; r < 4; r++) {
            int idx = r * 256 + t;
            int j = idx >> 3, c4 = idx & 7;
            float4 v = x4[((size_t)(b * Nv + i) * Nv + j0 + j) * 8 + c4];
            h4 hv; hv[0] = (_Float16)v.x; hv[1] = (_Float16)v.y;
            hv[2] = (_Float16)v.z; hv[3] = (_Float16)v.w;
            *(h4*)&Xt[j * XPAD + c4 * 4] = hv;
            float4 u = x4[((size_t)(b * Nv + j0 + j) * Nv + i) * 8 + c4];
            h4 hu; hu[0] = (_Float16)u.x; hu[1] = (_Float16)u.y;
            hu[2] = (_Float16)u.z; hu[3] = (_Float16)u.w;
            *(h4*)&Xb[j * XPAD + c4 * 4] = hu;
        }
    }
    int jl1 = w * 32 + rowA, jl2 = jl1 + 16;
    _Float16 e1h[4], e2h[4];
    {
        const float* ni = g_nb + (size_t)(b * Nv + i) * Mv;
        const float* n1 = g_nb + (size_t)(b * Nv + j0 + jl1) * Mv;
        const float* n2 = g_nb + (size_t)(b * Nv + j0 + jl2) * Mv;
        #pragma unroll
        for (int m = 0; m < 4; m++) {
            e1h[m] = (_Float16)(ni[m] * n1[m]);
            e2h[m] = (_Float16)(ni[m] * n2[m]);
        }
    }
    __syncthreads();

    f4 acc[2][4];
    #pragma unroll
    for (int js = 0; js < 2; js++)
        #pragma unroll
        for (int q = 0; q < 4; q++) acc[js][q] = {0.f, 0.f, 0.f, 0.f};

    const h8* Wf = (const h8*)Wl;
    #pragma unroll
    for (int part = 0; part < 2; part++) {
        const _Float16* X = part ? Xb : Xt;
        h8 xv1 = *(const h8*)&X[jl1 * XPAD + quad * 8];
        h8 xv2 = *(const h8*)&X[jl2 * XPAD + quad * 8];
        #pragma unroll
        for (int m = 0; m < 4; m++) {
            h8 a1 = xv1 * e1h[m];
            h8 a2 = xv2 * e2h[m];
            int s = part * 4 + m;
            #pragma unroll
            for (int q = 0; q < 4; q++) {
                h8 bf = Wf[(s * 4 + q) * 64 + lane];
                acc[0][q] = __builtin_amdgcn_mfma_f32_16x16x32_f16(a1, bf, acc[0][q], 0, 0, 0);
                acc[1][q] = __builtin_amdgcn_mfma_f32_16x16x32_f16(a2, bf, acc[1][q], 0, 0, 0);
            }
        }
    }
    #pragma unroll
    for (int js = 0; js < 2; js++) {
        int jbase = j0 + w * 32 + js * 16 + quad * 4;
        #pragma unroll
        for (int q = 0; q < 4; q++) {
            int o = q * 16 + rowA;
            #pragma unroll
            for (int r = 0; r < 4; r++) {
                int j = jbase + r;
                float v = acc[js][q][r] + g_addv[(size_t)(b * Nv + j) * OUTv + o];
                out[(((size_t)(b * Nv + i)) * Nv + j) * OUTv + o] = v;
            }
        }
    }
}

extern "C" void kernel_launch(void* const* d_in, const int* in_sizes, int n_in,
                              void* d_out, int out_size, void* d_ws, size_t ws_size,
                              hipStream_t stream) {
    const float* x     = (const float*)d_in[0];
    const float* w1_nb = (const float*)d_in[1];
    const float* b1_nb = (const float*)d_in[2];
    const float* w0_nb = (const float*)d_in[3];
    const float* b0_nb = (const float*)d_in[4];
    const float* w2d   = (const float*)d_in[5];
    const float* b2d   = (const float*)d_in[6];
    const float* w1d   = (const float*)d_in[7];
    const float* b1d   = (const float*)d_in[8];
    const float* w0d   = (const float*)d_in[9];
    const float* b0d   = (const float*)d_in[10];
    float* out = (float*)d_out;
    (void)d_ws; (void)ws_size;

    hipLaunchKernelGGL(k_wpackz, dim3(9), dim3(256), 0, stream, w2d);
    hipLaunchKernelGGL(k_passA, dim3(64, Bv), dim3(256), 0, stream, x);
    hipLaunchKernelGGL(k_neighb, dim3(Bv), dim3(256), 0, stream,
                       w1_nb, b1_nb, w0_nb, b0_nb);
    hipLaunchKernelGGL(k_passB, dim3(64, Bv), dim3(256), 0, stream, x);
    hipLaunchKernelGGL(k_t0, dim3(Bv), dim3(128), 0, stream, w0d, b0d);
    hipLaunchKernelGGL(k_add, dim3(Nv / 4, Bv), dim3(256), 0, stream,
                       w1d, b1d, b2d);
    hipLaunchKernelGGL(k_main, dim3(2, Nv, Bv), dim3(256), 0, stream, x, out);
}

// Round 6
// 185.051 us; speedup vs baseline: 1.3422x; 1.3422x over previous
//
#include <hip/hip_runtime.h>
#include <math.h>

#define Bv 4
#define Nv 256
#define Cv 32
#define Mv 4
#define OUTv 64
#define MCv (Mv*Cv)      // 128

typedef _Float16 h8 __attribute__((ext_vector_type(8)));
typedef _Float16 h4 __attribute__((ext_vector_type(4)));
typedef float f4 __attribute__((ext_vector_type(4)));

// ---- static device scratch ----
__device__ __align__(16) float g_rs  [Bv * Nv * Cv];
__device__ __align__(16) float g_cs  [Bv * Nv * Cv];
__device__ __align__(16) float g_dgx [Bv * Nv * Cv];
__device__ __align__(16) float g_nb  [Bv * Nv * Mv];
__device__ __align__(16) float g_S1  [Bv * Nv * MCv];
__device__ __align__(16) float g_S2  [Bv * Nv * MCv];
__device__ __align__(16) float g_rcs2[Bv * MCv];        // atomic accum
__device__ __align__(16) float g_ds2 [Bv * MCv];        // atomic accum
__device__ __align__(16) float g_t0g [Bv * OUTv];
__device__ __align__(16) float g_addv[Bv * Nv * OUTv];
__device__ __align__(16) _Float16 g_wfrag[8 * 4 * 64 * 8];   // 32 KB

// ---------------- K0: pack w2d -> f16 fragment order + zero accumulators ------
__global__ void k_wpackz(const float* __restrict__ w2d) {
    int t = threadIdx.x;
    int r = blockIdx.x;
    if (r == 8) {   // zero rcs2/ds2 (atomic accumulators)
        if (t < 128) ((float4*)g_rcs2)[t] = {0.f,0.f,0.f,0.f};
        else         ((float4*)g_ds2)[t - 128] = {0.f,0.f,0.f,0.f};
        return;
    }
    int fi = r * 256 + t;
    int s = fi >> 8, q = (fi >> 6) & 3, lane = fi & 63;
    int k0 = s * 32 + ((lane >> 4) << 3);
    int o = q * 16 + (lane & 15);
    #pragma unroll
    for (int jj = 0; jj < 8; jj++)
        g_wfrag[fi * 8 + jj] = (_Float16)w2d[(size_t)(k0 + jj) * OUTv + o];
}

// ---------------- K1: row/col/diag contractions, direction-split --------------
// bx < Nv : col-dir, n=bx: rs[n,c] = (1/N) sum_i x[i,n,c]; also dgx[n]
// bx >= Nv: row-dir, n=bx-Nv: cs[n,c] = (1/N) sum_j x[n,j,c]
__global__ __launch_bounds__(256) void k_contract1(const float* __restrict__ x) {
    int bx = blockIdx.x, b = blockIdx.y;
    int t = threadIdx.x, c4 = t & 7, sub = t >> 3;   // 32 subs x 8 float4-cols
    const float4* xb4 = (const float4*)(x + (size_t)b * Nv * Nv * Cv);
    __shared__ float red[32][36];
    float4 acc = {0.f,0.f,0.f,0.f};
    if (bx < Nv) {
        int n = bx;
        for (int i = sub; i < Nv; i += 32) {
            float4 v = xb4[((size_t)i * Nv + n) * 8 + c4];
            acc.x += v.x; acc.y += v.y; acc.z += v.z; acc.w += v.w;
        }
        red[sub][c4*4+0] = acc.x; red[sub][c4*4+1] = acc.y;
        red[sub][c4*4+2] = acc.z; red[sub][c4*4+3] = acc.w;
        __syncthreads();
        if (t < 32) {
            float s = 0.f;
            #pragma unroll
            for (int k = 0; k < 32; k++) s += red[k][t];
            g_rs[(b * Nv + n) * Cv + t] = s * (1.0f / Nv);
        }
        if (t < 8) ((float4*)g_dgx)[(b * Nv + n) * 8 + t] = xb4[((size_t)n * Nv + n) * 8 + t];
    } else {
        int n = bx - Nv;
        for (int j = sub; j < Nv; j += 32) {
            float4 v = xb4[((size_t)n * Nv + j) * 8 + c4];
            acc.x += v.x; acc.y += v.y; acc.z += v.z; acc.w += v.w;
        }
        red[sub][c4*4+0] = acc.x; red[sub][c4*4+1] = acc.y;
        red[sub][c4*4+2] = acc.z; red[sub][c4*4+3] = acc.w;
        __syncthreads();
        if (t < 32) {
            float s = 0.f;
            #pragma unroll
            for (int k = 0; k < 32; k++) s += red[k][t];
            g_cs[(b * Nv + n) * Cv + t] = s * (1.0f / Nv);
        }
    }
}

// ---------------- K2: neighborhood linear + sigmoid ----------------
__global__ void k_neighb(const float* __restrict__ w1, const float* __restrict__ b1,
                         const float* __restrict__ w0, const float* __restrict__ b0) {
    int b = blockIdx.x, t = threadIdx.x;
    int c = t & 31, sub = t >> 5;
    float ar = 0.f, ad = 0.f;
    for (int n = sub; n < Nv; n += 8) {
        ar += g_rs[(b * Nv + n) * Cv + c];
        ad += g_dgx[(b * Nv + n) * Cv + c];
    }
    __shared__ float red[8][64];
    __shared__ float obj0[64];
    __shared__ float t0nb[4];
    red[sub][c] = ar;
    red[sub][32 + c] = ad;
    __syncthreads();
    if (t < 64) {
        float s = 0.f;
        #pragma unroll
        for (int k = 0; k < 8; k++) s += red[k][t];
        obj0[t] = s * (1.0f / Nv);
    }
    __syncthreads();
    if (t < 4) {
        float v = b0[t];
        for (int k = 0; k < 2 * Cv; k++) v += obj0[k] * w0[k * Mv + t];
        t0nb[t] = v;
    }
    __syncthreads();
    int n = t;
    float node[4];
    #pragma unroll
    for (int m = 0; m < 4; m++) node[m] = t0nb[m] + b1[m];
    for (int cc = 0; cc < Cv; cc++) {
        float r = g_rs[(b * Nv + n) * Cv + cc];
        float s = g_cs[(b * Nv + n) * Cv + cc];
        float d = g_dgx[(b * Nv + n) * Cv + cc];
        #pragma unroll
        for (int m = 0; m < 4; m++)
            node[m] += r * w1[cc * Mv + m] + s * w1[(Cv + cc) * Mv + m] + d * w1[(2 * Cv + cc) * Mv + m];
    }
    #pragma unroll
    for (int m = 0; m < 4; m++)
        g_nb[(b * Nv + n) * Mv + m] = 1.0f / (1.0f + expf(-node[m]));
}

// ---------------- K3: nb-weighted sums, direction-split ----------------
// bx < Nv : col-dir, n=bx: S1[n,m,c] = sum_i nb[i,m] x[i,n,c]; + rcs2/ds2 atomics
// bx >= Nv: row-dir, n=bx-Nv: S2[n,m,c] = sum_j nb[j,m] x[n,j,c]
__global__ __launch_bounds__(256) void k_wsum(const float* __restrict__ x) {
    int bx = blockIdx.x, b = blockIdx.y;
    int t = threadIdx.x, c4 = t & 7, sub = t >> 3;
    __shared__ __align__(16) float4 nbl[Nv];
    if (t < Nv) nbl[t] = ((const float4*)(g_nb + (size_t)b * Nv * Mv))[t];
    __syncthreads();
    const float4* xb4 = (const float4*)(x + (size_t)b * Nv * Nv * Cv);
    float4 a[4];
    #pragma unroll
    for (int m = 0; m < 4; m++) a[m] = {0.f,0.f,0.f,0.f};
    __shared__ float red[32][132];
    if (bx < Nv) {
        int n = bx;
        for (int i = sub; i < Nv; i += 32) {
            float4 v = xb4[((size_t)i * Nv + n) * 8 + c4];
            float4 nv = nbl[i];
            a[0].x += nv.x*v.x; a[0].y += nv.x*v.y; a[0].z += nv.x*v.z; a[0].w += nv.x*v.w;
            a[1].x += nv.y*v.x; a[1].y += nv.y*v.y; a[1].z += nv.y*v.z; a[1].w += nv.y*v.w;
            a[2].x += nv.z*v.x; a[2].y += nv.z*v.y; a[2].z += nv.z*v.z; a[2].w += nv.z*v.w;
            a[3].x += nv.w*v.x; a[3].y += nv.w*v.y; a[3].z += nv.w*v.z; a[3].w += nv.w*v.w;
        }
        #pragma unroll
        for (int m = 0; m < 4; m++) {
            red[sub][m*32 + c4*4+0] = a[m].x; red[sub][m*32 + c4*4+1] = a[m].y;
            red[sub][m*32 + c4*4+2] = a[m].z; red[sub][m*32 + c4*4+3] = a[m].w;
        }
        __syncthreads();
        if (t < 128) {
            float s = 0.f;
            #pragma unroll
            for (int k = 0; k < 32; k++) s += red[k][t];
            g_S1[(size_t)(b * Nv + n) * MCv + t] = s;
            int m = t >> 5, c = t & 31;
            float nv = ((const float*)&nbl[n])[m];
            atomicAdd(&g_rcs2[b * MCv + t], nv * s);
            atomicAdd(&g_ds2 [b * MCv + t], nv * nv * g_dgx[(b * Nv + n) * Cv + c]);
        }
    } else {
        int n = bx - Nv;
        for (int j = sub; j < Nv; j += 32) {
            float4 v = xb4[((size_t)n * Nv + j) * 8 + c4];
            float4 nv = nbl[j];
            a[0].x += nv.x*v.x; a[0].y += nv.x*v.y; a[0].z += nv.x*v.z; a[0].w += nv.x*v.w;
            a[1].x += nv.y*v.x; a[1].y += nv.y*v.y; a[1].z += nv.y*v.z; a[1].w += nv.y*v.w;
            a[2].x += nv.z*v.x; a[2].y += nv.z*v.y; a[2].z += nv.z*v.z; a[2].w += nv.z*v.w;
            a[3].x += nv.w*v.x; a[3].y += nv.w*v.y; a[3].z += nv.w*v.z; a[3].w += nv.w*v.w;
        }
        #pragma unroll
        for (int m = 0; m < 4; m++) {
            red[sub][m*32 + c4*4+0] = a[m].x; red[sub][m*32 + c4*4+1] = a[m].y;
            red[sub][m*32 + c4*4+2] = a[m].z; red[sub][m*32 + c4*4+3] = a[m].w;
        }
        __syncthreads();
        if (t < 128) {
            float s = 0.f;
            #pragma unroll
            for (int k = 0; k < 32; k++) s += red[k][t];
            g_S2[(size_t)(b * Nv + n) * MCv + t] = s;
        }
    }
}

// ---------------- K4a: global term t0[b,o] (tiny matvec) ----------------
__global__ void k_t0(const float* __restrict__ w0d, const float* __restrict__ b0d) {
    int b = blockIdx.x, t = threadIdx.x;   // 128 threads
    __shared__ float rc[MCv], ds[MCv];
    rc[t] = g_rcs2[b * MCv + t] * (1.0f / ((float)Nv * Nv));
    ds[t] = g_ds2 [b * MCv + t] * (1.0f / Nv);
    __syncthreads();
    if (t < OUTv) {
        float v = b0d[t];
        for (int k = 0; k < MCv; k++)
            v += rc[k] * w0d[k * OUTv + t] + ds[k] * w0d[(MCv + k) * OUTv + t];
        g_t0g[b * OUTv + t] = v;
    }
}

// ---------------- K4b: per-column additive term, k-split ----------------
// add[b,n,o] = sum_mc [ nb/N*S1*w1d + nb/N*S2*w1d' + nb^2*dgx*w1d'' ] + biases
__global__ __launch_bounds__(256) void k_add(const float* __restrict__ w1d,
                                             const float* __restrict__ b1d,
                                             const float* __restrict__ b2d) {
    int b = blockIdx.y, n = blockIdx.x;
    int t = threadIdx.x, o = t & 63, ks = t >> 6;   // ks = wave = m
    __shared__ float red[4][64];
    const float invN = 1.0f / Nv;
    float nv = g_nb[(b * Nv + n) * Mv + ks];
    float f = nv * invN, d2 = nv * nv;
    const float* S1r = g_S1 + (size_t)(b * Nv + n) * MCv + ks * 32;
    const float* S2r = g_S2 + (size_t)(b * Nv + n) * MCv + ks * 32;
    const float* dgr = g_dgx + (size_t)(b * Nv + n) * Cv;
    float acc = 0.f;
    #pragma unroll 8
    for (int c = 0; c < 32; c++) {
        int mc = ks * 32 + c;
        acc += f * S1r[c] * w1d[(size_t)mc * OUTv + o]
             + f * S2r[c] * w1d[(size_t)(MCv + mc) * OUTv + o]
             + d2 * dgr[c] * w1d[(size_t)(2 * MCv + mc) * OUTv + o];
    }
    red[ks][o] = acc;
    __syncthreads();
    if (t < 64) {
        float v = red[0][t] + red[1][t] + red[2][t] + red[3][t]
                + b1d[t] + b2d[t] + g_t0g[b * OUTv + t];
        g_addv[(size_t)(b * Nv + n) * OUTv + t] = v;
    }
}

// ---------------- K5: main term via MFMA f16 ----------------
#define XPAD 40
__global__ __launch_bounds__(256) void k_main(const float* __restrict__ x,
                                              float* __restrict__ out) {
    int jt = blockIdx.x, i = blockIdx.y, b = blockIdx.z;
    int j0 = jt * 128;
    int t = threadIdx.x;
    int lane = t & 63, w = t >> 6;
    int rowA = lane & 15, quad = lane >> 4;

    __shared__ __align__(16) _Float16 Wl[8 * 4 * 64 * 8];   // 32 KB
    __shared__ __align__(16) _Float16 Xt[128 * XPAD];
    __shared__ __align__(16) _Float16 Xb[128 * XPAD];

    {
        const float4* src = (const float4*)g_wfrag;
        float4* dst = (float4*)Wl;
        #pragma unroll
        for (int r = 0; r < 8; r++) dst[r * 256 + t] = src[r * 256 + t];
    }
    {
        const float4* x4 = (const float4*)x;
        #pragma unroll
        for (int r = 0; r < 4; r++) {
            int idx = r * 256 + t;
            int j = idx >> 3, c4 = idx & 7;
            float4 v = x4[((size_t)(b * Nv + i) * Nv + j0 + j) * 8 + c4];
            h4 hv; hv[0] = (_Float16)v.x; hv[1] = (_Float16)v.y;
            hv[2] = (_Float16)v.z; hv[3] = (_Float16)v.w;
            *(h4*)&Xt[j * XPAD + c4 * 4] = hv;
            float4 u = x4[((size_t)(b * Nv + j0 + j) * Nv + i) * 8 + c4];
            h4 hu; hu[0] = (_Float16)u.x; hu[1] = (_Float16)u.y;
            hu[2] = (_Float16)u.z; hu[3] = (_Float16)u.w;
            *(h4*)&Xb[j * XPAD + c4 * 4] = hu;
        }
    }
    int jl1 = w * 32 + rowA, jl2 = jl1 + 16;
    _Float16 e1h[4], e2h[4];
    {
        const float* ni = g_nb + (size_t)(b * Nv + i) * Mv;
        const float* n1 = g_nb + (size_t)(b * Nv + j0 + jl1) * Mv;
        const float* n2 = g_nb + (size_t)(b * Nv + j0 + jl2) * Mv;
        #pragma unroll
        for (int m = 0; m < 4; m++) {
            e1h[m] = (_Float16)(ni[m] * n1[m]);
            e2h[m] = (_Float16)(ni[m] * n2[m]);
        }
    }
    __syncthreads();

    f4 acc[2][4];
    #pragma unroll
    for (int js = 0; js < 2; js++)
        #pragma unroll
        for (int q = 0; q < 4; q++) acc[js][q] = {0.f, 0.f, 0.f, 0.f};

    const h8* Wf = (const h8*)Wl;
    #pragma unroll
    for (int part = 0; part < 2; part++) {
        const _Float16* X = part ? Xb : Xt;
        h8 xv1 = *(const h8*)&X[jl1 * XPAD + quad * 8];
        h8 xv2 = *(const h8*)&X[jl2 * XPAD + quad * 8];
        #pragma unroll
        for (int m = 0; m < 4; m++) {
            h8 a1 = xv1 * e1h[m];
            h8 a2 = xv2 * e2h[m];
            int s = part * 4 + m;
            #pragma unroll
            for (int q = 0; q < 4; q++) {
                h8 bf = Wf[(s * 4 + q) * 64 + lane];
                acc[0][q] = __builtin_amdgcn_mfma_f32_16x16x32_f16(a1, bf, acc[0][q], 0, 0, 0);
                acc[1][q] = __builtin_amdgcn_mfma_f32_16x16x32_f16(a2, bf, acc[1][q], 0, 0, 0);
            }
        }
    }
    #pragma unroll
    for (int js = 0; js < 2; js++) {
        int jbase = j0 + w * 32 + js * 16 + quad * 4;
        #pragma unroll
        for (int q = 0; q < 4; q++) {
            int o = q * 16 + rowA;
            #pragma unroll
            for (int r = 0; r < 4; r++) {
                int j = jbase + r;
                float v = acc[js][q][r] + g_addv[(size_t)(b * Nv + j) * OUTv + o];
                out[(((size_t)(b * Nv + i)) * Nv + j) * OUTv + o] = v;
            }
        }
    }
}

extern "C" void kernel_launch(void* const* d_in, const int* in_sizes, int n_in,
                              void* d_out, int out_size, void* d_ws, size_t ws_size,
                              hipStream_t stream) {
    const float* x     = (const float*)d_in[0];
    const float* w1_nb = (const float*)d_in[1];
    const float* b1_nb = (const float*)d_in[2];
    const float* w0_nb = (const float*)d_in[3];
    const float* b0_nb = (const float*)d_in[4];
    const float* w2d   = (const float*)d_in[5];
    const float* b2d   = (const float*)d_in[6];
    const float* w1d   = (const float*)d_in[7];
    const float* b1d   = (const float*)d_in[8];
    const float* w0d   = (const float*)d_in[9];
    const float* b0d   = (const float*)d_in[10];
    float* out = (float*)d_out;
    (void)d_ws; (void)ws_size;

    hipLaunchKernelGGL(k_wpackz, dim3(9), dim3(256), 0, stream, w2d);
    hipLaunchKernelGGL(k_contract1, dim3(2 * Nv, Bv), dim3(256), 0, stream, x);
    hipLaunchKernelGGL(k_neighb, dim3(Bv), dim3(256), 0, stream,
                       w1_nb, b1_nb, w0_nb, b0_nb);
    hipLaunchKernelGGL(k_wsum, dim3(2 * Nv, Bv), dim3(256), 0, stream, x);
    hipLaunchKernelGGL(k_t0, dim3(Bv), dim3(128), 0, stream, w0d, b0d);
    hipLaunchKernelGGL(k_add, dim3(Nv, Bv), dim3(256), 0, stream,
                       w1d, b1d, b2d);
    hipLaunchKernelGGL(k_main, dim3(2, Nv, Bv), dim3(256), 0, stream, x, out);
}